// Round 10
// baseline (159.518 us; speedup 1.0000x reference)
//
#include <hip/hip_runtime.h>
#include <hip/hip_bf16.h>

#define NB 2
#define NPTS 5000
#define DIM 128
#define G 64
#define NCELL (G*G)
#define HCELL (1.0f/G)
#define MEAN_OFF (2*5001*128)

/* ws float layout:
   [0..895]      folded weights A(3x128), Bm(3x128), c(128)
   [1024..41023] nbrsum: 10000 rows x 4 floats
   int region at float offset WS_INT_F:
     cellStart: NB*(NCELL+1)   (flat exclusive prefix + total sentinel)
     cursor:    NB*NCELL       (counts, then scatter cursors)
     ptsJ:      NB*NPTS        (original index of sorted point)
   float2 region at WS_XY_F (even => 8B aligned): ptsXY NB*NPTS           */
#define WS_INT_F 41024
#define OFF_CSTART 0
#define OFF_CURSOR (NB*(NCELL+1))
#define OFF_PTSJ   (OFF_CURSOR + NB*NCELL)
#define N_INTS     (OFF_PTSJ + NB*NPTS)
#define WS_XY_F    (WS_INT_F + N_INTS)   /* 67410, even */

// ---------------- Kernel 1: folded weights + depot rows + mean init + zero counters
__global__ __launch_bounds__(256) void pre_kernel(
    const float* __restrict__ W_init, const float* __restrict__ b_init,
    const float* __restrict__ W_nbr,  const float* __restrict__ b_nbr,
    const float* __restrict__ W_depot,const float* __restrict__ b_depot,
    const float* __restrict__ W_final,const float* __restrict__ b_final,
    const float* __restrict__ depot,
    float* __restrict__ ws, float* __restrict__ out) {
  const int tid = threadIdx.x;
  int* __restrict__ cz = (int*)(ws + WS_INT_F) + OFF_CURSOR;
  for (int idx = tid; idx < NB*NCELL; idx += 256) cz[idx] = 0;
  for (int idx = tid; idx < 768; idx += 256) {
    const float* Ws = (idx < 384) ? W_init : W_nbr;
    int rem = (idx >= 384) ? idx - 384 : idx;
    int t = rem >> 7, d = rem & 127;
    float acc = 0.f;
#pragma unroll 8
    for (int e = 0; e < 128; ++e) acc += Ws[t*128 + e] * W_final[e*128 + d];
    ws[idx] = acc;
  }
  if (tid < 128) {
    float acc = 0.f;
#pragma unroll 8
    for (int e = 0; e < 128; ++e) acc += (b_init[e] + 6.f*b_nbr[e]) * W_final[e*128 + tid];
    ws[768 + tid] = acc + 7.f*b_final[tid];
  }
  {
    int b = tid >> 7, d = tid & 127;
    float val = depot[b*2] * W_depot[d] + depot[b*2+1] * W_depot[128 + d] + b_depot[d];
    out[(size_t)b*5001*128 + d] = val;                    // h[b,0,:]
    out[MEAN_OFF + b*128 + d]   = val * (1.f/5001.f);     // mean init (depot term)
  }
}

__device__ __forceinline__ int cell_of(float v) {
  int c = (int)(v * (float)G);
  return c < 0 ? 0 : (c > G-1 ? G-1 : c);
}

// ---------------- Kernel 2: per-cell counts (into cursor)
__global__ __launch_bounds__(256) void count_kernel(
    const float* __restrict__ loc, int* __restrict__ ints) {
  int tid = blockIdx.x*256 + threadIdx.x;
  if (tid >= NB*NPTS) return;
  int b = tid >= NPTS;
  float2 p = ((const float2*)loc)[tid];
  int c = cell_of(p.y)*G + cell_of(p.x);
  atomicAdd(&ints[OFF_CURSOR + b*NCELL + c], 1);
}

// ---------------- Kernel 3: exclusive prefix scan per batch; cursor := start
__global__ __launch_bounds__(1024) void scan_kernel(int* __restrict__ ints) {
  const int b = blockIdx.x, t = threadIdx.x;
  __shared__ int part[1024];
  int* cnt = ints + OFF_CURSOR + b*NCELL;
  int* cst = ints + OFF_CSTART + b*(NCELL+1);
  int c0 = cnt[4*t], c1 = cnt[4*t+1], c2 = cnt[4*t+2], c3 = cnt[4*t+3];
  int tot = c0+c1+c2+c3;
  part[t] = tot;
  __syncthreads();
  for (int off = 1; off < 1024; off <<= 1) {
    int v = (t >= off) ? part[t-off] : 0;
    __syncthreads();
    part[t] += v;
    __syncthreads();
  }
  int base = part[t] - tot;              // exclusive prefix of this thread
  cst[4*t]   = base;            cnt[4*t]   = base;
  cst[4*t+1] = base+c0;         cnt[4*t+1] = base+c0;
  cst[4*t+2] = base+c0+c1;      cnt[4*t+2] = base+c0+c1;
  cst[4*t+3] = base+c0+c1+c2;   cnt[4*t+3] = base+c0+c1+c2;
  if (t == 1023) cst[NCELL] = part[1023];
}

// ---------------- Kernel 4: scatter points into cell-sorted order
__global__ __launch_bounds__(256) void scatter_kernel(
    const float* __restrict__ loc, int* __restrict__ ints,
    float2* __restrict__ xy) {
  int tid = blockIdx.x*256 + threadIdx.x;
  if (tid >= NB*NPTS) return;
  int b = tid >= NPTS;
  int i = tid - b*NPTS;
  float2 p = ((const float2*)loc)[tid];
  int c = cell_of(p.y)*G + cell_of(p.x);
  int pos = atomicAdd(&ints[OFF_CURSOR + b*NCELL + c], 1);
  xy[b*NPTS + pos] = p;
  ints[OFF_PTSJ + b*NPTS + pos] = i;
}

// Keys pack (dist_bits<<32)|global_j: strict u64 '<' == stable argsort order.
#define PACK(d_, j_) ((((unsigned long long)__float_as_uint(d_)) << 32) | (unsigned)(j_))
#define KINIT 0x7f800000ffffffffULL
#define INS6(nk) \
  { bool c_; unsigned long long t_; \
    c_ = nk<k0; t_=k0; k0=c_?nk:k0; nk=c_?t_:nk; \
    c_ = nk<k1; t_=k1; k1=c_?nk:k1; nk=c_?t_:nk; \
    c_ = nk<k2; t_=k2; k2=c_?nk:k2; nk=c_?t_:nk; \
    c_ = nk<k3; t_=k3; k3=c_?nk:k3; nk=c_?t_:nk; \
    c_ = nk<k4; t_=k4; k4=c_?nk:k4; nk=c_?t_:nk; \
    c_ = nk<k5; k5=c_?nk:k5; }

// ---------------- Kernel 5: grid 6-NN, all points LDS-staged + batch-0 gather
__global__ __launch_bounds__(256) void knn_grid(
    const float* __restrict__ loc, const float* __restrict__ deadline,
    const int* __restrict__ ints, const float2* __restrict__ xy,
    float* __restrict__ nbrsum) {
  const int b = blockIdx.y;
  __shared__ float2 sxy[NPTS];           // 40 KB
  __shared__ int    sj[NPTS];            // 20 KB
  const float2* XY = xy + b*NPTS;
  const int*    J  = ints + OFF_PTSJ + b*NPTS;
  for (int k = threadIdx.x; k < NPTS; k += 256) { sxy[k] = XY[k]; sj[k] = J[k]; }
  __syncthreads();

  const int s = blockIdx.x*256 + threadIdx.x;   // sorted slot
  if (s >= NPTS) return;
  const int* cs = ints + OFF_CSTART + b*(NCELL+1);

  const float2 q = sxy[s];
  const int qi = sj[s];
  const int cx = cell_of(q.x), cy = cell_of(q.y);

  unsigned long long k0=KINIT,k1=KINIT,k2=KINIT,k3=KINIT,k4=KINIT,k5=KINIT;

#define SCAN_CELL(cidx) \
  { int p0 = cs[cidx], p1 = cs[(cidx)+1]; \
    for (int p = p0; p < p1; ++p) { \
      float2 t = sxy[p]; \
      float dx = q.x - t.x, dy = q.y - t.y; \
      float ss = __fadd_rn(__fmul_rn(dx,dx), __fmul_rn(dy,dy)); \
      float nd = sqrtf(ss); \
      unsigned long long nk = PACK(nd, (unsigned)sj[p]); \
      if (nk < k5) { INS6(nk); } } }

  // box radius 2 (clipped)
  {
    int x0 = cx-2 < 0 ? 0 : cx-2, x1 = cx+2 > G-1 ? G-1 : cx+2;
    int y0 = cy-2 < 0 ? 0 : cy-2, y1 = cy+2 > G-1 ? G-1 : cy+2;
    for (int y = y0; y <= y1; ++y)
      for (int x = x0; x <= x1; ++x) SCAN_CELL(y*G + x);
  }
  // ring expansion until provably done:
  // all unscanned cells are >= Rb+1 Chebyshev rings away => true dist > Rb*HCELL
  int Rb = 2;
  while (true) {
    float d6 = __uint_as_float((unsigned)(k5 >> 32));
    if (0.999999f * ((float)Rb * HCELL) > d6) break;
    ++Rb;
    if (Rb > G) break;                  // whole grid scanned by now
    int xa = cx-Rb < 0 ? 0 : cx-Rb, xb = cx+Rb > G-1 ? G-1 : cx+Rb;
    int yt = cy-Rb, yb = cy+Rb;
    if (yt >= 0)   { for (int x = xa; x <= xb; ++x) SCAN_CELL(yt*G + x); }
    if (yb <= G-1) { for (int x = xa; x <= xb; ++x) SCAN_CELL(yb*G + x); }
    int ya = cy-Rb+1 < 0 ? 0 : cy-Rb+1, yz = cy+Rb-1 > G-1 ? G-1 : cy+Rb-1;
    if (cx-Rb >= 0)   { for (int y = ya; y <= yz; ++y) SCAN_CELL(y*G + (cx-Rb)); }
    if (cx+Rb <= G-1) { for (int y = ya; y <= yz; ++y) SCAN_CELL(y*G + (cx+Rb)); }
  }

  // gather from batch-0 x (the reference's x[0][neighbors] quirk)
  float s0=0.f, s1=0.f, s2=0.f;
  { int j=(int)(unsigned)k0; s0+=loc[j*2]; s1+=loc[j*2+1]; s2+=deadline[j]; }
  { int j=(int)(unsigned)k1; s0+=loc[j*2]; s1+=loc[j*2+1]; s2+=deadline[j]; }
  { int j=(int)(unsigned)k2; s0+=loc[j*2]; s1+=loc[j*2+1]; s2+=deadline[j]; }
  { int j=(int)(unsigned)k3; s0+=loc[j*2]; s1+=loc[j*2+1]; s2+=deadline[j]; }
  { int j=(int)(unsigned)k4; s0+=loc[j*2]; s1+=loc[j*2+1]; s2+=deadline[j]; }
  { int j=(int)(unsigned)k5; s0+=loc[j*2]; s1+=loc[j*2+1]; s2+=deadline[j]; }
  const size_t o = ((size_t)b*NPTS + qi) * 4;   // ORIGINAL row index
  nbrsum[o] = s0; nbrsum[o+1] = s1; nbrsum[o+2] = s2;
}

// ---------------- Kernel 6: h rows + mean accumulation
__global__ __launch_bounds__(256) void rows_kernel(
    const float* __restrict__ loc, const float* __restrict__ deadline,
    const float* __restrict__ ws, float* __restrict__ out) {
  const int b  = blockIdx.y;
  const int d  = threadIdx.x & 127;
  const int rs = threadIdx.x >> 7;
  const float A0 = ws[d],      A1 = ws[128+d], A2 = ws[256+d];
  const float B0 = ws[384+d],  B1 = ws[512+d], B2 = ws[640+d];
  const float cc = ws[768+d];
  const float* __restrict__ nbrsum = ws + 1024;
  float msum = 0.f;
#pragma unroll
  for (int it = 0; it < 8; ++it) {
    int i = blockIdx.x*16 + it*2 + rs;
    if (i < NPTS) {
      size_t r = (size_t)b*NPTS + i;
      float u0 = loc[r*2], u1 = loc[r*2+1], u2 = deadline[r];
      float w0 = nbrsum[r*4]   - 6.f*u0;
      float w1 = nbrsum[r*4+1] - 6.f*u1;
      float w2 = nbrsum[r*4+2] - 6.f*u2;
      float val = cc + u0*A0 + u1*A1 + u2*A2 + w0*B0 + w1*B1 + w2*B2;
      out[((size_t)b*5001 + 1 + i)*128 + d] = val;
      msum += val;
    }
  }
  atomicAdd(&out[MEAN_OFF + b*128 + d], msum * (1.f/5001.f));
}

extern "C" void kernel_launch(void* const* d_in, const int* in_sizes, int n_in,
                              void* d_out, int out_size, void* d_ws, size_t ws_size,
                              hipStream_t stream) {
  const float* loc      = (const float*)d_in[0];
  const float* deadline = (const float*)d_in[1];
  const float* depot    = (const float*)d_in[2];
  const float* W_init   = (const float*)d_in[3];
  const float* b_init   = (const float*)d_in[4];
  const float* W_nbr    = (const float*)d_in[5];
  const float* b_nbr    = (const float*)d_in[6];
  const float* W_depot  = (const float*)d_in[7];
  const float* b_depot  = (const float*)d_in[8];
  const float* W_final  = (const float*)d_in[9];
  const float* b_final  = (const float*)d_in[10];
  float* out = (float*)d_out;
  float* ws  = (float*)d_ws;
  int*    ints = (int*)(ws + WS_INT_F);
  float2* xy   = (float2*)(ws + WS_XY_F);

  hipLaunchKernelGGL(pre_kernel, dim3(1), dim3(256), 0, stream,
                     W_init, b_init, W_nbr, b_nbr, W_depot, b_depot,
                     W_final, b_final, depot, ws, out);
  hipLaunchKernelGGL(count_kernel, dim3((NB*NPTS + 255)/256), dim3(256), 0, stream,
                     loc, ints);
  hipLaunchKernelGGL(scan_kernel, dim3(NB), dim3(1024), 0, stream, ints);
  hipLaunchKernelGGL(scatter_kernel, dim3((NB*NPTS + 255)/256), dim3(256), 0, stream,
                     loc, ints, xy);
  hipLaunchKernelGGL(knn_grid, dim3((NPTS + 255)/256, NB), dim3(256), 0, stream,
                     loc, deadline, ints, xy, ws + 1024);
  hipLaunchKernelGGL(rows_kernel, dim3((NPTS + 15)/16, NB), dim3(256), 0, stream,
                     loc, deadline, ws, out);
}

// Round 11
// 133.939 us; speedup vs baseline: 1.1910x; 1.1910x over previous
//
#include <hip/hip_runtime.h>
#include <hip/hip_bf16.h>

#define NB 2
#define NPTS 5000
#define DIM 128
#define G 64
#define NCELL (G*G)
#define HCELL (1.0f/G)
#define MEAN_OFF (2*5001*128)

/* ws float layout:
   [0..895]      folded weights A(3x128), Bm(3x128), c(128)
   [1024..41023] nbrsum: 10000 rows x 4 floats
   int region at float offset WS_INT_F:
     cellStart: NB*(NCELL+1)   (flat exclusive prefix + total sentinel)
     cursor:    NB*NCELL       (counts, then scatter cursors)
     ptsJ:      NB*NPTS        (original index of sorted point)
   float2 region at WS_XY_F (even => 8B aligned): ptsXY NB*NPTS           */
#define WS_INT_F 41024
#define OFF_CSTART 0
#define OFF_CURSOR (NB*(NCELL+1))
#define OFF_PTSJ   (OFF_CURSOR + NB*NCELL)
#define N_INTS     (OFF_PTSJ + NB*NPTS)
#define WS_XY_F    (WS_INT_F + N_INTS)   /* 67410, even */

// ---------------- Kernel 1: folded weights + depot rows + mean init + zero counters
// grid(4): blocks 0..2 -> one folded-weight row each (256 outputs, ILP-4 dot);
// block 3 -> bias fold + depot rows + counter zeroing.
__global__ __launch_bounds__(256) void pre_kernel(
    const float* __restrict__ W_init, const float* __restrict__ b_init,
    const float* __restrict__ W_nbr,  const float* __restrict__ b_nbr,
    const float* __restrict__ W_depot,const float* __restrict__ b_depot,
    const float* __restrict__ W_final,const float* __restrict__ b_final,
    const float* __restrict__ depot,
    float* __restrict__ ws, float* __restrict__ out) {
  const int tid = threadIdx.x;
  const int blk = blockIdx.x;
  if (blk < 3) {
    // outputs [blk*256, blk*256+256) of the 768 folded-weight entries
    int idx = blk*256 + tid;
    const float* Ws = (idx < 384) ? W_init : W_nbr;
    int rem = (idx >= 384) ? idx - 384 : idx;
    int t = rem >> 7, d = rem & 127;
    float a0=0.f, a1=0.f, a2=0.f, a3=0.f;
#pragma unroll 8
    for (int e = 0; e < 128; e += 4) {
      a0 += Ws[t*128 + e]   * W_final[(e)*128 + d];
      a1 += Ws[t*128 + e+1] * W_final[(e+1)*128 + d];
      a2 += Ws[t*128 + e+2] * W_final[(e+2)*128 + d];
      a3 += Ws[t*128 + e+3] * W_final[(e+3)*128 + d];
    }
    ws[idx] = (a0+a1)+(a2+a3);
    return;
  }
  // block 3: counters, bias fold, depot rows
  int* __restrict__ cz = (int*)(ws + WS_INT_F) + OFF_CURSOR;
  for (int idx = tid; idx < NB*NCELL; idx += 256) cz[idx] = 0;
  if (tid < 128) {
    float a0=0.f, a1=0.f, a2=0.f, a3=0.f;
#pragma unroll 8
    for (int e = 0; e < 128; e += 4) {
      a0 += (b_init[e]   + 6.f*b_nbr[e])   * W_final[(e)*128 + tid];
      a1 += (b_init[e+1] + 6.f*b_nbr[e+1]) * W_final[(e+1)*128 + tid];
      a2 += (b_init[e+2] + 6.f*b_nbr[e+2]) * W_final[(e+2)*128 + tid];
      a3 += (b_init[e+3] + 6.f*b_nbr[e+3]) * W_final[(e+3)*128 + tid];
    }
    ws[768 + tid] = (a0+a1)+(a2+a3) + 7.f*b_final[tid];
  }
  {
    int b = tid >> 7, d = tid & 127;
    float val = depot[b*2] * W_depot[d] + depot[b*2+1] * W_depot[128 + d] + b_depot[d];
    out[(size_t)b*5001*128 + d] = val;                    // h[b,0,:]
    out[MEAN_OFF + b*128 + d]   = val * (1.f/5001.f);     // mean init (depot term)
  }
}

__device__ __forceinline__ int cell_of(float v) {
  int c = (int)(v * (float)G);
  return c < 0 ? 0 : (c > G-1 ? G-1 : c);
}

// ---------------- Kernel 2: per-cell counts (into cursor)
__global__ __launch_bounds__(256) void count_kernel(
    const float* __restrict__ loc, int* __restrict__ ints) {
  int tid = blockIdx.x*256 + threadIdx.x;
  if (tid >= NB*NPTS) return;
  int b = tid >= NPTS;
  float2 p = ((const float2*)loc)[tid];
  int c = cell_of(p.y)*G + cell_of(p.x);
  atomicAdd(&ints[OFF_CURSOR + b*NCELL + c], 1);
}

// ---------------- Kernel 3: exclusive prefix scan per batch; cursor := start
__global__ __launch_bounds__(1024) void scan_kernel(int* __restrict__ ints) {
  const int b = blockIdx.x, t = threadIdx.x;
  __shared__ int part[1024];
  int* cnt = ints + OFF_CURSOR + b*NCELL;
  int* cst = ints + OFF_CSTART + b*(NCELL+1);
  int c0 = cnt[4*t], c1 = cnt[4*t+1], c2 = cnt[4*t+2], c3 = cnt[4*t+3];
  int tot = c0+c1+c2+c3;
  part[t] = tot;
  __syncthreads();
  for (int off = 1; off < 1024; off <<= 1) {
    int v = (t >= off) ? part[t-off] : 0;
    __syncthreads();
    part[t] += v;
    __syncthreads();
  }
  int base = part[t] - tot;              // exclusive prefix of this thread
  cst[4*t]   = base;            cnt[4*t]   = base;
  cst[4*t+1] = base+c0;         cnt[4*t+1] = base+c0;
  cst[4*t+2] = base+c0+c1;      cnt[4*t+2] = base+c0+c1;
  cst[4*t+3] = base+c0+c1+c2;   cnt[4*t+3] = base+c0+c1+c2;
  if (t == 1023) cst[NCELL] = part[1023];
}

// ---------------- Kernel 4: scatter points into cell-sorted order
__global__ __launch_bounds__(256) void scatter_kernel(
    const float* __restrict__ loc, int* __restrict__ ints,
    float2* __restrict__ xy) {
  int tid = blockIdx.x*256 + threadIdx.x;
  if (tid >= NB*NPTS) return;
  int b = tid >= NPTS;
  int i = tid - b*NPTS;
  float2 p = ((const float2*)loc)[tid];
  int c = cell_of(p.y)*G + cell_of(p.x);
  int pos = atomicAdd(&ints[OFF_CURSOR + b*NCELL + c], 1);
  xy[b*NPTS + pos] = p;
  ints[OFF_PTSJ + b*NPTS + pos] = i;
}

// Keys pack (dist_bits<<32)|global_j: strict u64 '<' == stable argsort order.
#define PACK(d_, j_) ((((unsigned long long)__float_as_uint(d_)) << 32) | (unsigned)(j_))
#define KINIT 0x7f800000ffffffffULL
#define INS6(nk) \
  { bool c_; unsigned long long t_; \
    c_ = nk<k0; t_=k0; k0=c_?nk:k0; nk=c_?t_:nk; \
    c_ = nk<k1; t_=k1; k1=c_?nk:k1; nk=c_?t_:nk; \
    c_ = nk<k2; t_=k2; k2=c_?nk:k2; nk=c_?t_:nk; \
    c_ = nk<k3; t_=k3; k3=c_?nk:k3; nk=c_?t_:nk; \
    c_ = nk<k4; t_=k4; k4=c_?nk:k4; nk=c_?t_:nk; \
    c_ = nk<k5; k5=c_?nk:k5; }

// scan a contiguous sorted-point range [p0,p1) from LDS
#define SCAN_RANGE(p0_, p1_) \
  for (int p = (p0_); p < (p1_); ++p) { \
    float2 t = sxy[p]; \
    float dx = q.x - t.x, dy = q.y - t.y; \
    float ss = __fadd_rn(__fmul_rn(dx,dx), __fmul_rn(dy,dy)); \
    float nd = sqrtf(ss); \
    unsigned long long nk = PACK(nd, (unsigned)sj[p]); \
    if (nk < k5) { INS6(nk); } }

// ---------------- Kernel 5: grid 6-NN. Row-major cells => a row of the box is
// ONE contiguous sorted-point range. 5x5 box = 5 ranges, 10 cs loads issued
// upfront (independent, pipelined) instead of 25 serialized per-cell gathers.
__global__ __launch_bounds__(256) void knn_grid(
    const float* __restrict__ loc, const float* __restrict__ deadline,
    const int* __restrict__ ints, const float2* __restrict__ xy,
    float* __restrict__ nbrsum) {
  const int b = blockIdx.y;
  __shared__ float2 sxy[NPTS];           // 40 KB
  __shared__ int    sj[NPTS];            // 20 KB
  const float2* XY = xy + b*NPTS;
  const int*    J  = ints + OFF_PTSJ + b*NPTS;
  for (int k = threadIdx.x; k < NPTS; k += 256) { sxy[k] = XY[k]; sj[k] = J[k]; }
  __syncthreads();

  const int s = blockIdx.x*256 + threadIdx.x;   // sorted slot
  if (s >= NPTS) return;
  const int* __restrict__ cs = ints + OFF_CSTART + b*(NCELL+1);

  const float2 q = sxy[s];
  const int qi = sj[s];
  const int cx = cell_of(q.x), cy = cell_of(q.y);
  const int x0 = cx-2 < 0 ? 0 : cx-2, x1 = cx+2 > G-1 ? G-1 : cx+2;

  unsigned long long k0=KINIT,k1=KINIT,k2=KINIT,k3=KINIT,k4=KINIT,k5=KINIT;

  // ---- box radius 2: load all 5 row-range bounds upfront (static unroll,
  // stays in registers; empty range for clipped rows)
  int rb0,re0,rb1,re1,rb2,re2,rb3,re3,rb4,re4;
  {
    int y;
    y = cy-2; if (y >= 0 && y <= G-1) { rb0 = cs[y*G+x0]; re0 = cs[y*G+x1+1]; } else { rb0 = 0; re0 = 0; }
    y = cy-1; if (y >= 0 && y <= G-1) { rb1 = cs[y*G+x0]; re1 = cs[y*G+x1+1]; } else { rb1 = 0; re1 = 0; }
    y = cy;                           { rb2 = cs[y*G+x0]; re2 = cs[y*G+x1+1]; }
    y = cy+1; if (y >= 0 && y <= G-1) { rb3 = cs[y*G+x0]; re3 = cs[y*G+x1+1]; } else { rb3 = 0; re3 = 0; }
    y = cy+2; if (y >= 0 && y <= G-1) { rb4 = cs[y*G+x0]; re4 = cs[y*G+x1+1]; } else { rb4 = 0; re4 = 0; }
  }
  SCAN_RANGE(rb0, re0);
  SCAN_RANGE(rb1, re1);
  SCAN_RANGE(rb2, re2);
  SCAN_RANGE(rb3, re3);
  SCAN_RANGE(rb4, re4);

  // ---- ring expansion until provably done: all unscanned cells are >= Rb+1
  // Chebyshev rings away => true dist > Rb*HCELL (cell scale exact in f32)
  int Rb = 2;
  while (true) {
    float d6 = __uint_as_float((unsigned)(k5 >> 32));
    if (0.999999f * ((float)Rb * HCELL) > d6) break;
    ++Rb;
    if (Rb > G) break;                  // whole grid scanned by now
    int xa = cx-Rb < 0 ? 0 : cx-Rb, xb = cx+Rb > G-1 ? G-1 : cx+Rb;
    int yt = cy-Rb, yb = cy+Rb;
    if (yt >= 0)   { int p0 = cs[yt*G+xa], p1 = cs[yt*G+xb+1]; SCAN_RANGE(p0, p1); }
    if (yb <= G-1) { int p0 = cs[yb*G+xa], p1 = cs[yb*G+xb+1]; SCAN_RANGE(p0, p1); }
    int ya = cy-Rb+1 < 0 ? 0 : cy-Rb+1, yz = cy+Rb-1 > G-1 ? G-1 : cy+Rb-1;
    if (cx-Rb >= 0)   { for (int y = ya; y <= yz; ++y) { int p0 = cs[y*G+(cx-Rb)], p1 = cs[y*G+(cx-Rb)+1]; SCAN_RANGE(p0, p1); } }
    if (cx+Rb <= G-1) { for (int y = ya; y <= yz; ++y) { int p0 = cs[y*G+(cx+Rb)], p1 = cs[y*G+(cx+Rb)+1]; SCAN_RANGE(p0, p1); } }
  }

  // gather from batch-0 x (the reference's x[0][neighbors] quirk)
  float s0=0.f, s1=0.f, s2=0.f;
  { int j=(int)(unsigned)k0; s0+=loc[j*2]; s1+=loc[j*2+1]; s2+=deadline[j]; }
  { int j=(int)(unsigned)k1; s0+=loc[j*2]; s1+=loc[j*2+1]; s2+=deadline[j]; }
  { int j=(int)(unsigned)k2; s0+=loc[j*2]; s1+=loc[j*2+1]; s2+=deadline[j]; }
  { int j=(int)(unsigned)k3; s0+=loc[j*2]; s1+=loc[j*2+1]; s2+=deadline[j]; }
  { int j=(int)(unsigned)k4; s0+=loc[j*2]; s1+=loc[j*2+1]; s2+=deadline[j]; }
  { int j=(int)(unsigned)k5; s0+=loc[j*2]; s1+=loc[j*2+1]; s2+=deadline[j]; }
  const size_t o = ((size_t)b*NPTS + qi) * 4;   // ORIGINAL row index
  nbrsum[o] = s0; nbrsum[o+1] = s1; nbrsum[o+2] = s2;
}

// ---------------- Kernel 6: h rows + mean accumulation
__global__ __launch_bounds__(256) void rows_kernel(
    const float* __restrict__ loc, const float* __restrict__ deadline,
    const float* __restrict__ ws, float* __restrict__ out) {
  const int b  = blockIdx.y;
  const int d  = threadIdx.x & 127;
  const int rs = threadIdx.x >> 7;
  const float A0 = ws[d],      A1 = ws[128+d], A2 = ws[256+d];
  const float B0 = ws[384+d],  B1 = ws[512+d], B2 = ws[640+d];
  const float cc = ws[768+d];
  const float* __restrict__ nbrsum = ws + 1024;
  float msum = 0.f;
#pragma unroll
  for (int it = 0; it < 8; ++it) {
    int i = blockIdx.x*16 + it*2 + rs;
    if (i < NPTS) {
      size_t r = (size_t)b*NPTS + i;
      float u0 = loc[r*2], u1 = loc[r*2+1], u2 = deadline[r];
      float w0 = nbrsum[r*4]   - 6.f*u0;
      float w1 = nbrsum[r*4+1] - 6.f*u1;
      float w2 = nbrsum[r*4+2] - 6.f*u2;
      float val = cc + u0*A0 + u1*A1 + u2*A2 + w0*B0 + w1*B1 + w2*B2;
      out[((size_t)b*5001 + 1 + i)*128 + d] = val;
      msum += val;
    }
  }
  atomicAdd(&out[MEAN_OFF + b*128 + d], msum * (1.f/5001.f));
}

extern "C" void kernel_launch(void* const* d_in, const int* in_sizes, int n_in,
                              void* d_out, int out_size, void* d_ws, size_t ws_size,
                              hipStream_t stream) {
  const float* loc      = (const float*)d_in[0];
  const float* deadline = (const float*)d_in[1];
  const float* depot    = (const float*)d_in[2];
  const float* W_init   = (const float*)d_in[3];
  const float* b_init   = (const float*)d_in[4];
  const float* W_nbr    = (const float*)d_in[5];
  const float* b_nbr    = (const float*)d_in[6];
  const float* W_depot  = (const float*)d_in[7];
  const float* b_depot  = (const float*)d_in[8];
  const float* W_final  = (const float*)d_in[9];
  const float* b_final  = (const float*)d_in[10];
  float* out = (float*)d_out;
  float* ws  = (float*)d_ws;
  int*    ints = (int*)(ws + WS_INT_F);
  float2* xy   = (float2*)(ws + WS_XY_F);

  hipLaunchKernelGGL(pre_kernel, dim3(4), dim3(256), 0, stream,
                     W_init, b_init, W_nbr, b_nbr, W_depot, b_depot,
                     W_final, b_final, depot, ws, out);
  hipLaunchKernelGGL(count_kernel, dim3((NB*NPTS + 255)/256), dim3(256), 0, stream,
                     loc, ints);
  hipLaunchKernelGGL(scan_kernel, dim3(NB), dim3(1024), 0, stream, ints);
  hipLaunchKernelGGL(scatter_kernel, dim3((NB*NPTS + 255)/256), dim3(256), 0, stream,
                     loc, ints, xy);
  hipLaunchKernelGGL(knn_grid, dim3((NPTS + 255)/256, NB), dim3(256), 0, stream,
                     loc, deadline, ints, xy, ws + 1024);
  hipLaunchKernelGGL(rows_kernel, dim3((NPTS + 15)/16, NB), dim3(256), 0, stream,
                     loc, deadline, ws, out);
}